// Round 4
// baseline (299.034 us; speedup 1.0000x reference)
//
#include <hip/hip_runtime.h>

typedef __attribute__((ext_vector_type(8))) short short8;
typedef __attribute__((ext_vector_type(4))) float f32x4;
typedef __attribute__((ext_vector_type(4))) unsigned int u32x4;

namespace {

constexpr int kS = 16384;
constexpr int kD = 64;
constexpr int kH = 16;
// LDS row strides: stride/16B ODD -> balanced bank-quad coverage for b128
constexpr int KSTR = 72;   // shorts per K-tile row   (144 B = 9 quads)
constexpr int VSTR = 40;   // shorts per Vt row       (80 B  = 5 quads)
constexpr int PSTR = 36;   // u32 per P row           (144 B = 9 quads; 32 data + 4 pad)

__device__ inline unsigned short bf16hi(float x) {
  return (unsigned short)(__builtin_bit_cast(unsigned int, x) >> 16);
}
__device__ inline float hipart(float x) {
  return __builtin_bit_cast(float, __builtin_bit_cast(unsigned int, x) & 0xFFFF0000u);
}
// 8 fp32 -> hi/lo bf16 split (truncation; lo captures the residual)
__device__ inline void cvt8(float4 a, float4 b, short8& hi, short8& lo) {
  float f[8] = {a.x, a.y, a.z, a.w, b.x, b.y, b.z, b.w};
#pragma unroll
  for (int i = 0; i < 8; ++i) {
    hi[i] = (short)bf16hi(f[i]);
    lo[i] = (short)bf16hi(f[i] - hipart(f[i]));
  }
}

#define MFMA(a, b, c) __builtin_amdgcn_mfma_f32_16x16x32_bf16(a, b, c, 0, 0, 0)

__global__ __launch_bounds__(256, 4)
void lf_attn_mfma(const float* __restrict__ Q, const float* __restrict__ K,
                  const float* __restrict__ V, const float* __restrict__ M,
                  float* __restrict__ O) {
  __shared__ short Khi[32 * KSTR], Klo[32 * KSTR];        // 9.2 KB
  __shared__ short Vthi[64 * VSTR], Vtlo[64 * VSTR];      // 10.2 KB
  __shared__ unsigned int Pint[4][32 * PSTR];             // 18.4 KB (hi|lo<<16)

  const int tid = threadIdx.x;
  const int w  = tid >> 6;        // wave 0..3
  const int l  = tid & 63;
  const int g  = l >> 4;          // 16-lane group 0..3
  const int lk = l & 15;
  const int qs = blockIdx.x * 128;
  const int h  = blockIdx.y;
  const size_t hb = (size_t)h * kS * kD;
  const int klo_ = (qs >= 128) ? qs - 128 : 0;
  const int ntiles = (qs + 128 - klo_) >> 5;   // 4 or 8
  const int qw = qs + w * 32;                  // this wave's first q row

  // ---- Q fragments (hi/lo) straight from global into registers ----
  short8 qhi[2][2], qlo[2][2];
#pragma unroll
  for (int qt = 0; qt < 2; ++qt)
#pragma unroll
    for (int ds = 0; ds < 2; ++ds) {
      const float* qp = Q + hb + (size_t)(qw + 16 * qt + lk) * kD + 32 * ds + 8 * g;
      float4 a = *(const float4*)qp;
      float4 b = *(const float4*)(qp + 4);
      cvt8(a, b, qhi[qt][ds], qlo[qt][ds]);
    }

  f32x4 zero4 = {0.f, 0.f, 0.f, 0.f};
  f32x4 oacc[2][4];
#pragma unroll
  for (int qt = 0; qt < 2; ++qt)
#pragma unroll
    for (int dt = 0; dt < 4; ++dt) oacc[qt][dt] = zero4;
  f32x4 lsum[2] = {zero4, zero4};

  // staging registers (K: row tid>>3, d (tid&7)*8; V: row tid&31, d (tid>>5)*8)
  const int skk = tid >> 3, skd = (tid & 7) * 8;
  const int svk = tid & 31, svd = (tid >> 5) * 8;
  float4 ka0, ka1, va0, va1;

  auto stage_load = [&](int k0) {
    const float* kp = K + hb + (size_t)(k0 + skk) * kD + skd;
    ka0 = *(const float4*)kp;  ka1 = *(const float4*)(kp + 4);
    const float* vp = V + hb + (size_t)(k0 + svk) * kD + svd;
    va0 = *(const float4*)vp;  va1 = *(const float4*)(vp + 4);
  };
  auto stage_write = [&]() {
    short8 h8, l8;
    cvt8(ka0, ka1, h8, l8);
    *(short8*)&Khi[skk * KSTR + skd] = h8;
    *(short8*)&Klo[skk * KSTR + skd] = l8;
    cvt8(va0, va1, h8, l8);
#pragma unroll
    for (int j = 0; j < 8; ++j) {
      Vthi[(svd + j) * VSTR + svk] = h8[j];
      Vtlo[(svd + j) * VSTR + svk] = l8[j];
    }
  };

  // prologue: stage tile 0
  stage_load(klo_);
  stage_write();
  __syncthreads();

  for (int tt = 0; tt < ntiles; ++tt) {
    const int k0 = klo_ + tt * 32;
    const bool have_next = (tt + 1 < ntiles);
    if (have_next) stage_load(klo_ + (tt + 1) * 32);   // issue early (T14)

    if (k0 <= qw + 31) {   // wave-uniform skip of fully-masked tiles
      // ---- QK^T: 3-way hi/lo split ----
      f32x4 sacc[2][2];
#pragma unroll
      for (int qt = 0; qt < 2; ++qt)
#pragma unroll
        for (int kt = 0; kt < 2; ++kt) sacc[qt][kt] = zero4;
#pragma unroll
      for (int kt = 0; kt < 2; ++kt)
#pragma unroll
        for (int ds = 0; ds < 2; ++ds) {
          short8 kh = *(const short8*)&Khi[(16 * kt + lk) * KSTR + 32 * ds + 8 * g];
          short8 kl = *(const short8*)&Klo[(16 * kt + lk) * KSTR + 32 * ds + 8 * g];
#pragma unroll
          for (int qt = 0; qt < 2; ++qt) {
            sacc[qt][kt] = MFMA(qhi[qt][ds], kh, sacc[qt][kt]);
            sacc[qt][kt] = MFMA(qhi[qt][ds], kl, sacc[qt][kt]);
            sacc[qt][kt] = MFMA(qlo[qt][ds], kh, sacc[qt][kt]);
          }
        }

      // ---- softmax (no-max: scores bounded << 88) + pack P hi/lo ----
      const float mv0 = M[k0 + lk];
      const float mv1 = M[k0 + 16 + lk];
#pragma unroll
      for (int qt = 0; qt < 2; ++qt) {
        f32x4 pr[2];
#pragma unroll
        for (int kt = 0; kt < 2; ++kt) {
          const int kg = k0 + 16 * kt + lk;
          const float mv = kt ? mv1 : mv0;
          f32x4 p;
#pragma unroll
          for (int r = 0; r < 4; ++r) {
            const int qg = qw + 16 * qt + 4 * g + r;
            p[r] = (kg <= qg) ? __expf(sacc[qt][kt][r] + mv) : 0.f;
          }
          pr[kt] = p;
#pragma unroll
          for (int r = 0; r < 4; ++r) {
            unsigned hh = bf16hi(p[r]);
            unsigned ll = bf16hi(p[r] - hipart(p[r]));
            Pint[w][(16 * qt + 4 * g + r) * PSTR + 16 * kt + lk] = hh | (ll << 16);
          }
        }
        f32x4 rs = pr[0] + pr[1];
#pragma unroll
        for (int m = 1; m <= 8; m <<= 1) {
#pragma unroll
          for (int r = 0; r < 4; ++r) rs[r] += __shfl_xor(rs[r], m, 64);
        }
        lsum[qt] += rs;
      }

      // ---- PV: 3-way hi/lo split ----
      short8 vh[4], vl[4];
#pragma unroll
      for (int dt = 0; dt < 4; ++dt) {
        vh[dt] = *(const short8*)&Vthi[(16 * dt + lk) * VSTR + 8 * g];
        vl[dt] = *(const short8*)&Vtlo[(16 * dt + lk) * VSTR + 8 * g];
      }
#pragma unroll
      for (int qt = 0; qt < 2; ++qt) {
        const unsigned int* prow = &Pint[w][(16 * qt + lk) * PSTR + 8 * g];
        u32x4 x0 = *(const u32x4*)prow;
        u32x4 x1 = *(const u32x4*)(prow + 4);
        u32x4 hu, lu;
        hu[0] = __builtin_amdgcn_perm(x0[1], x0[0], 0x05040100u);
        lu[0] = __builtin_amdgcn_perm(x0[1], x0[0], 0x07060302u);
        hu[1] = __builtin_amdgcn_perm(x0[3], x0[2], 0x05040100u);
        lu[1] = __builtin_amdgcn_perm(x0[3], x0[2], 0x07060302u);
        hu[2] = __builtin_amdgcn_perm(x1[1], x1[0], 0x05040100u);
        lu[2] = __builtin_amdgcn_perm(x1[1], x1[0], 0x07060302u);
        hu[3] = __builtin_amdgcn_perm(x1[3], x1[2], 0x05040100u);
        lu[3] = __builtin_amdgcn_perm(x1[3], x1[2], 0x07060302u);
        short8 ph = __builtin_bit_cast(short8, hu);
        short8 pl = __builtin_bit_cast(short8, lu);
#pragma unroll
        for (int dt = 0; dt < 4; ++dt) {
          oacc[qt][dt] = MFMA(ph, vh[dt], oacc[qt][dt]);
          oacc[qt][dt] = MFMA(pl, vh[dt], oacc[qt][dt]);
          oacc[qt][dt] = MFMA(ph, vl[dt], oacc[qt][dt]);
        }
      }
    }

    __syncthreads();                    // all waves done reading K/Vt
    if (have_next) stage_write();       // overwrite single buffer
    __syncthreads();                    // writes visible
  }

  // ---- epilogue: normalize and store ----
#pragma unroll
  for (int qt = 0; qt < 2; ++qt) {
    f32x4 inv;
#pragma unroll
    for (int r = 0; r < 4; ++r) inv[r] = 1.0f / lsum[qt][r];
#pragma unroll
    for (int dt = 0; dt < 4; ++dt)
#pragma unroll
      for (int r = 0; r < 4; ++r)
        O[hb + (size_t)(qw + 16 * qt + 4 * g + r) * kD + 16 * dt + lk] =
            oacc[qt][dt][r] * inv[r];
  }
}

} // namespace

extern "C" void kernel_launch(void* const* d_in, const int* in_sizes, int n_in,
                              void* d_out, int out_size, void* d_ws, size_t ws_size,
                              hipStream_t stream) {
  const float* Q = (const float*)d_in[0];
  const float* K = (const float*)d_in[1];
  const float* V = (const float*)d_in[2];
  const float* M = (const float*)d_in[3];
  float* O = (float*)d_out;
  dim3 grid(kS / 128, kH);
  dim3 block(256);
  hipLaunchKernelGGL(lf_attn_mfma, grid, block, 0, stream, Q, K, V, M, O);
}

// Round 5
// 259.301 us; speedup vs baseline: 1.1532x; 1.1532x over previous
//
#include <hip/hip_runtime.h>

typedef __attribute__((ext_vector_type(8))) short short8;
typedef __attribute__((ext_vector_type(4))) float f32x4;
typedef __attribute__((ext_vector_type(4))) unsigned int u32x4;

namespace {

constexpr int kS = 16384;
constexpr int kD = 64;
constexpr int kH = 16;
// LDS row strides: stride/16B ODD -> balanced bank-quad coverage for b128
constexpr int KSTR = 72;   // shorts per K-tile row   (144 B = 9 quads)
constexpr int VSTR = 40;   // shorts per Vt row       (80 B  = 5 quads)
constexpr int PSTR = 36;   // u32 per P row           (144 B = 9 quads; 32 data + 4 pad)

__device__ inline unsigned short bf16hi(float x) {
  return (unsigned short)(__builtin_bit_cast(unsigned int, x) >> 16);
}
__device__ inline float hipart(float x) {
  return __builtin_bit_cast(float, __builtin_bit_cast(unsigned int, x) & 0xFFFF0000u);
}
// 8 fp32 -> hi/lo bf16 split (truncation; lo captures the residual)
__device__ inline void cvt8(float4 a, float4 b, short8& hi, short8& lo) {
  float f[8] = {a.x, a.y, a.z, a.w, b.x, b.y, b.z, b.w};
#pragma unroll
  for (int i = 0; i < 8; ++i) {
    hi[i] = (short)bf16hi(f[i]);
    lo[i] = (short)bf16hi(f[i] - hipart(f[i]));
  }
}

#define MFMA(a, b, c) __builtin_amdgcn_mfma_f32_16x16x32_bf16(a, b, c, 0, 0, 0)

// NOTE: (256,2): (256,4) capped unified VGPR+AGPR at 128 -> scratch spills,
// +285 MB HBM traffic, 130->175us regression (R4). Registers are the binding
// resource; LDS=37.9KB already allows 3-4 blocks/CU at ~140 total regs.
__global__ __launch_bounds__(256, 2)
void lf_attn_mfma(const float* __restrict__ Q, const float* __restrict__ K,
                  const float* __restrict__ V, const float* __restrict__ M,
                  float* __restrict__ O) {
  __shared__ short Khi[32 * KSTR], Klo[32 * KSTR];        // 9.2 KB
  __shared__ short Vthi[64 * VSTR], Vtlo[64 * VSTR];      // 10.2 KB
  __shared__ unsigned int Pint[4][32 * PSTR];             // 18.4 KB (hi|lo<<16)

  const int tid = threadIdx.x;
  const int w  = tid >> 6;        // wave 0..3
  const int l  = tid & 63;
  const int g  = l >> 4;          // 16-lane group 0..3
  const int lk = l & 15;
  const int qs = blockIdx.x * 128;
  const int h  = blockIdx.y;
  const size_t hb = (size_t)h * kS * kD;
  const int klo_ = (qs >= 128) ? qs - 128 : 0;
  const int ntiles = (qs + 128 - klo_) >> 5;   // 4 or 8
  const int qw = qs + w * 32;                  // this wave's first q row

  // ---- Q fragments (hi/lo) straight from global into registers ----
  short8 qhi[2][2], qlo[2][2];
#pragma unroll
  for (int qt = 0; qt < 2; ++qt)
#pragma unroll
    for (int ds = 0; ds < 2; ++ds) {
      const float* qp = Q + hb + (size_t)(qw + 16 * qt + lk) * kD + 32 * ds + 8 * g;
      float4 a = *(const float4*)qp;
      float4 b = *(const float4*)(qp + 4);
      cvt8(a, b, qhi[qt][ds], qlo[qt][ds]);
    }

  f32x4 zero4 = {0.f, 0.f, 0.f, 0.f};
  f32x4 oacc[2][4];
#pragma unroll
  for (int qt = 0; qt < 2; ++qt)
#pragma unroll
    for (int dt = 0; dt < 4; ++dt) oacc[qt][dt] = zero4;
  f32x4 lsum[2] = {zero4, zero4};

  // staging registers (K: row tid>>3, d (tid&7)*8; V: row tid&31, d (tid>>5)*8)
  const int skk = tid >> 3, skd = (tid & 7) * 8;
  const int svk = tid & 31, svd = (tid >> 5) * 8;
  float4 ka0, ka1, va0, va1;

  auto stage_load = [&](int k0) {
    const float* kp = K + hb + (size_t)(k0 + skk) * kD + skd;
    ka0 = *(const float4*)kp;  ka1 = *(const float4*)(kp + 4);
    const float* vp = V + hb + (size_t)(k0 + svk) * kD + svd;
    va0 = *(const float4*)vp;  va1 = *(const float4*)(vp + 4);
  };
  auto stage_write = [&]() {
    short8 h8, l8;
    cvt8(ka0, ka1, h8, l8);
    *(short8*)&Khi[skk * KSTR + skd] = h8;
    *(short8*)&Klo[skk * KSTR + skd] = l8;
    cvt8(va0, va1, h8, l8);
#pragma unroll
    for (int j = 0; j < 8; ++j) {
      Vthi[(svd + j) * VSTR + svk] = h8[j];
      Vtlo[(svd + j) * VSTR + svk] = l8[j];
    }
  };

  // prologue: stage tile 0
  stage_load(klo_);
  stage_write();
  __syncthreads();

  for (int tt = 0; tt < ntiles; ++tt) {
    const int k0 = klo_ + tt * 32;
    const bool have_next = (tt + 1 < ntiles);
    if (have_next) stage_load(klo_ + (tt + 1) * 32);   // issue early (T14)

    if (k0 <= qw + 31) {   // wave-uniform skip of fully-masked tiles
      // ---- QK^T: 3-way hi/lo split ----
      f32x4 sacc[2][2];
#pragma unroll
      for (int qt = 0; qt < 2; ++qt)
#pragma unroll
        for (int kt = 0; kt < 2; ++kt) sacc[qt][kt] = zero4;
#pragma unroll
      for (int kt = 0; kt < 2; ++kt)
#pragma unroll
        for (int ds = 0; ds < 2; ++ds) {
          short8 kh = *(const short8*)&Khi[(16 * kt + lk) * KSTR + 32 * ds + 8 * g];
          short8 kl = *(const short8*)&Klo[(16 * kt + lk) * KSTR + 32 * ds + 8 * g];
#pragma unroll
          for (int qt = 0; qt < 2; ++qt) {
            sacc[qt][kt] = MFMA(qhi[qt][ds], kh, sacc[qt][kt]);
            sacc[qt][kt] = MFMA(qhi[qt][ds], kl, sacc[qt][kt]);
            sacc[qt][kt] = MFMA(qlo[qt][ds], kh, sacc[qt][kt]);
          }
        }

      // ---- softmax (no-max: scores bounded << 88) + pack P hi/lo ----
      const float mv0 = M[k0 + lk];
      const float mv1 = M[k0 + 16 + lk];
#pragma unroll
      for (int qt = 0; qt < 2; ++qt) {
        f32x4 pr[2];
#pragma unroll
        for (int kt = 0; kt < 2; ++kt) {
          const int kg = k0 + 16 * kt + lk;
          const float mv = kt ? mv1 : mv0;
          f32x4 p;
#pragma unroll
          for (int r = 0; r < 4; ++r) {
            const int qg = qw + 16 * qt + 4 * g + r;
            p[r] = (kg <= qg) ? __expf(sacc[qt][kt][r] + mv) : 0.f;
          }
          pr[kt] = p;
#pragma unroll
          for (int r = 0; r < 4; ++r) {
            unsigned hh = bf16hi(p[r]);
            unsigned ll = bf16hi(p[r] - hipart(p[r]));
            Pint[w][(16 * qt + 4 * g + r) * PSTR + 16 * kt + lk] = hh | (ll << 16);
          }
        }
        f32x4 rs = pr[0] + pr[1];
#pragma unroll
        for (int m = 1; m <= 8; m <<= 1) {
#pragma unroll
          for (int r = 0; r < 4; ++r) rs[r] += __shfl_xor(rs[r], m, 64);
        }
        lsum[qt] += rs;
      }

      // ---- PV: 3-way hi/lo split; V frags loaded per-dt to cap live regs ----
#pragma unroll
      for (int qt = 0; qt < 2; ++qt) {
        const unsigned int* prow = &Pint[w][(16 * qt + lk) * PSTR + 8 * g];
        u32x4 x0 = *(const u32x4*)prow;
        u32x4 x1 = *(const u32x4*)(prow + 4);
        u32x4 hu, lu;
        hu[0] = __builtin_amdgcn_perm(x0[1], x0[0], 0x05040100u);
        lu[0] = __builtin_amdgcn_perm(x0[1], x0[0], 0x07060302u);
        hu[1] = __builtin_amdgcn_perm(x0[3], x0[2], 0x05040100u);
        lu[1] = __builtin_amdgcn_perm(x0[3], x0[2], 0x07060302u);
        hu[2] = __builtin_amdgcn_perm(x1[1], x1[0], 0x05040100u);
        lu[2] = __builtin_amdgcn_perm(x1[1], x1[0], 0x07060302u);
        hu[3] = __builtin_amdgcn_perm(x1[3], x1[2], 0x05040100u);
        lu[3] = __builtin_amdgcn_perm(x1[3], x1[2], 0x07060302u);
        short8 ph = __builtin_bit_cast(short8, hu);
        short8 pl = __builtin_bit_cast(short8, lu);
#pragma unroll
        for (int dt = 0; dt < 4; ++dt) {
          short8 vh = *(const short8*)&Vthi[(16 * dt + lk) * VSTR + 8 * g];
          short8 vl = *(const short8*)&Vtlo[(16 * dt + lk) * VSTR + 8 * g];
          oacc[qt][dt] = MFMA(ph, vh, oacc[qt][dt]);
          oacc[qt][dt] = MFMA(pl, vh, oacc[qt][dt]);
          oacc[qt][dt] = MFMA(ph, vl, oacc[qt][dt]);
        }
      }
    }

    __syncthreads();                    // all waves done reading K/Vt
    if (have_next) stage_write();       // overwrite single buffer
    __syncthreads();                    // writes visible
  }

  // ---- epilogue: normalize and store ----
#pragma unroll
  for (int qt = 0; qt < 2; ++qt) {
    f32x4 inv;
#pragma unroll
    for (int r = 0; r < 4; ++r) inv[r] = 1.0f / lsum[qt][r];
#pragma unroll
    for (int dt = 0; dt < 4; ++dt)
#pragma unroll
      for (int r = 0; r < 4; ++r)
        O[hb + (size_t)(qw + 16 * qt + 4 * g + r) * kD + 16 * dt + lk] =
            oacc[qt][dt][r] * inv[r];
  }
}

} // namespace

extern "C" void kernel_launch(void* const* d_in, const int* in_sizes, int n_in,
                              void* d_out, int out_size, void* d_ws, size_t ws_size,
                              hipStream_t stream) {
  const float* Q = (const float*)d_in[0];
  const float* K = (const float*)d_in[1];
  const float* V = (const float*)d_in[2];
  const float* M = (const float*)d_in[3];
  float* O = (float*)d_out;
  dim3 grid(kS / 128, kH);
  dim3 block(256);
  hipLaunchKernelGGL(lf_attn_mfma, grid, block, 0, stream, Q, K, V, M, O);
}

// Round 6
// 258.366 us; speedup vs baseline: 1.1574x; 1.0036x over previous
//
#include <hip/hip_runtime.h>

typedef __attribute__((ext_vector_type(8))) short short8;
typedef __attribute__((ext_vector_type(4))) short short4v;
typedef __attribute__((ext_vector_type(4))) float f32x4;
typedef __attribute__((ext_vector_type(4))) unsigned int u32x4;

namespace {

constexpr int kS = 16384;
constexpr int kD = 64;
constexpr int kH = 16;
// LDS row strides: stride/16B ODD -> balanced bank-quad coverage for b128
constexpr int KSTR = 72;   // shorts per K-tile row   (144 B = 9 quads)
constexpr int VSTR = 40;   // shorts per Vt row       (80 B  = 5 quads)
constexpr int PSTR = 36;   // u32 per P row           (144 B = 9 quads; 32 data + 4 pad)

__device__ inline unsigned short bf16hi(float x) {
  return (unsigned short)(__builtin_bit_cast(unsigned int, x) >> 16);
}
__device__ inline float hipart(float x) {
  return __builtin_bit_cast(float, __builtin_bit_cast(unsigned int, x) & 0xFFFF0000u);
}
// 4 fp32 -> hi/lo bf16 split (truncation; lo captures the residual)
__device__ inline void cvt4(float4 a, short4v& hi, short4v& lo) {
  float f[4] = {a.x, a.y, a.z, a.w};
#pragma unroll
  for (int i = 0; i < 4; ++i) {
    hi[i] = (short)bf16hi(f[i]);
    lo[i] = (short)bf16hi(f[i] - hipart(f[i]));
  }
}

#define MFMA(a, b, c) __builtin_amdgcn_mfma_f32_16x16x32_bf16(a, b, c, 0, 0, 0)

// 8 waves x 16 q-rows per 512-thread block (128 q-rows, minimal 2x K/V refetch).
// R5 lesson: binding resource is unified VGPR+AGPR (~190/wave at 32 rows/wave
// -> 2 blks/CU, 20% occ). 16 rows/wave needs ~100 regs -> (512,4) caps at 128
// -> 2 blocks x 8 waves = 50% occupancy without spills (R4 spilled at 128 cap
// only because the 32-row layout needs ~160).
__global__ __launch_bounds__(512, 4)
void lf_attn_mfma(const float* __restrict__ Q, const float* __restrict__ K,
                  const float* __restrict__ V, const float* __restrict__ M,
                  float* __restrict__ O) {
  __shared__ short Khi[32 * KSTR], Klo[32 * KSTR];        // 9.2 KB
  __shared__ short Vthi[64 * VSTR], Vtlo[64 * VSTR];      // 10.2 KB
  __shared__ unsigned int Pint[8][16 * PSTR];             // 18.4 KB (hi|lo<<16)

  const int tid = threadIdx.x;
  const int w  = tid >> 6;        // wave 0..7
  const int l  = tid & 63;
  const int g  = l >> 4;          // 16-lane group 0..3
  const int lk = l & 15;
  const int qs = blockIdx.x * 128;
  const int h  = blockIdx.y;
  const size_t hb = (size_t)h * kS * kD;
  const int klo_ = (qs >= 128) ? qs - 128 : 0;
  const int ntiles = (qs + 128 - klo_) >> 5;   // 4 or 8
  const int qw = qs + w * 16;                  // this wave's first q row

  // ---- Q fragments (hi/lo) straight from global into registers ----
  short8 qhi[2], qlo[2];
#pragma unroll
  for (int ds = 0; ds < 2; ++ds) {
    const float* qp = Q + hb + (size_t)(qw + lk) * kD + 32 * ds + 8 * g;
    float4 a = *(const float4*)qp;
    float4 b = *(const float4*)(qp + 4);
    short4v h0, l0, h1, l1;
    cvt4(a, h0, l0);
    cvt4(b, h1, l1);
#pragma unroll
    for (int i = 0; i < 4; ++i) {
      qhi[ds][i] = h0[i];     qlo[ds][i] = l0[i];
      qhi[ds][4+i] = h1[i];   qlo[ds][4+i] = l1[i];
    }
  }

  f32x4 zero4 = {0.f, 0.f, 0.f, 0.f};
  f32x4 oacc[4];
#pragma unroll
  for (int dt = 0; dt < 4; ++dt) oacc[dt] = zero4;
  f32x4 lsum = zero4;

  // staging: 512 threads, 1 float4 of K + 1 float4 of V each
  const int skk = tid >> 4, skd = (tid & 15) * 4;   // K row 0..31, col 0..60
  const int svk = tid & 31, svd = (tid >> 5) * 4;   // V row 0..31, col 0..60
  float4 ka, va;

  auto stage_load = [&](int k0) {
    ka = *(const float4*)(K + hb + (size_t)(k0 + skk) * kD + skd);
    va = *(const float4*)(V + hb + (size_t)(k0 + svk) * kD + svd);
  };
  auto stage_write = [&]() {
    short4v h4, l4;
    cvt4(ka, h4, l4);
    *(short4v*)&Khi[skk * KSTR + skd] = h4;
    *(short4v*)&Klo[skk * KSTR + skd] = l4;
    cvt4(va, h4, l4);
#pragma unroll
    for (int j = 0; j < 4; ++j) {
      Vthi[(svd + j) * VSTR + svk] = h4[j];
      Vtlo[(svd + j) * VSTR + svk] = l4[j];
    }
  };

  // prologue: stage tile 0
  stage_load(klo_);
  stage_write();
  __syncthreads();

  for (int tt = 0; tt < ntiles; ++tt) {
    const int k0 = klo_ + tt * 32;
    const bool have_next = (tt + 1 < ntiles);
    if (have_next) stage_load(klo_ + (tt + 1) * 32);   // issue early (T14)

    if (k0 <= qw + 15) {   // wave-uniform skip of fully-masked tiles
      // ---- QK^T: 3-way hi/lo split ----
      f32x4 sacc[2] = {zero4, zero4};
#pragma unroll
      for (int kt = 0; kt < 2; ++kt)
#pragma unroll
        for (int ds = 0; ds < 2; ++ds) {
          short8 kh = *(const short8*)&Khi[(16 * kt + lk) * KSTR + 32 * ds + 8 * g];
          short8 kl = *(const short8*)&Klo[(16 * kt + lk) * KSTR + 32 * ds + 8 * g];
          sacc[kt] = MFMA(qhi[ds], kh, sacc[kt]);
          sacc[kt] = MFMA(qhi[ds], kl, sacc[kt]);
          sacc[kt] = MFMA(qlo[ds], kh, sacc[kt]);
        }

      // ---- softmax (no-max: scores bounded << 88) + pack P hi/lo ----
      f32x4 pr[2];
#pragma unroll
      for (int kt = 0; kt < 2; ++kt) {
        const int kg = k0 + 16 * kt + lk;
        const float mv = M[kg];
        f32x4 p;
#pragma unroll
        for (int r = 0; r < 4; ++r) {
          const int qg = qw + 4 * g + r;
          p[r] = (kg <= qg) ? __expf(sacc[kt][r] + mv) : 0.f;
        }
        pr[kt] = p;
#pragma unroll
        for (int r = 0; r < 4; ++r) {
          unsigned hh = bf16hi(p[r]);
          unsigned ll = bf16hi(p[r] - hipart(p[r]));
          Pint[w][(4 * g + r) * PSTR + 16 * kt + lk] = hh | (ll << 16);
        }
      }
      {
        f32x4 rs = pr[0] + pr[1];
#pragma unroll
        for (int m = 1; m <= 8; m <<= 1) {
#pragma unroll
          for (int r = 0; r < 4; ++r) rs[r] += __shfl_xor(rs[r], m, 64);
        }
        lsum += rs;
      }

      // ---- PV: 3-way hi/lo split; V frags loaded per-dt to cap live regs ----
      const unsigned int* prow = &Pint[w][lk * PSTR + 8 * g];
      u32x4 x0 = *(const u32x4*)prow;
      u32x4 x1 = *(const u32x4*)(prow + 4);
      u32x4 hu, lu;
      hu[0] = __builtin_amdgcn_perm(x0[1], x0[0], 0x05040100u);
      lu[0] = __builtin_amdgcn_perm(x0[1], x0[0], 0x07060302u);
      hu[1] = __builtin_amdgcn_perm(x0[3], x0[2], 0x05040100u);
      lu[1] = __builtin_amdgcn_perm(x0[3], x0[2], 0x07060302u);
      hu[2] = __builtin_amdgcn_perm(x1[1], x1[0], 0x05040100u);
      lu[2] = __builtin_amdgcn_perm(x1[1], x1[0], 0x07060302u);
      hu[3] = __builtin_amdgcn_perm(x1[3], x1[2], 0x05040100u);
      lu[3] = __builtin_amdgcn_perm(x1[3], x1[2], 0x07060302u);
      short8 ph = __builtin_bit_cast(short8, hu);
      short8 pl = __builtin_bit_cast(short8, lu);
#pragma unroll
      for (int dt = 0; dt < 4; ++dt) {
        short8 vh = *(const short8*)&Vthi[(16 * dt + lk) * VSTR + 8 * g];
        short8 vl = *(const short8*)&Vtlo[(16 * dt + lk) * VSTR + 8 * g];
        oacc[dt] = MFMA(ph, vh, oacc[dt]);
        oacc[dt] = MFMA(pl, vh, oacc[dt]);
        oacc[dt] = MFMA(ph, vl, oacc[dt]);
      }
    }

    __syncthreads();                    // all waves done reading K/Vt
    if (have_next) stage_write();       // overwrite single buffer
    __syncthreads();                    // writes visible
  }

  // ---- epilogue: normalize and store ----
  f32x4 inv;
#pragma unroll
  for (int r = 0; r < 4; ++r) inv[r] = 1.0f / lsum[r];
#pragma unroll
  for (int dt = 0; dt < 4; ++dt)
#pragma unroll
    for (int r = 0; r < 4; ++r)
      O[hb + (size_t)(qw + 4 * g + r) * kD + 16 * dt + lk] = oacc[dt][r] * inv[r];
}

} // namespace

extern "C" void kernel_launch(void* const* d_in, const int* in_sizes, int n_in,
                              void* d_out, int out_size, void* d_ws, size_t ws_size,
                              hipStream_t stream) {
  const float* Q = (const float*)d_in[0];
  const float* K = (const float*)d_in[1];
  const float* V = (const float*)d_in[2];
  const float* M = (const float*)d_in[3];
  float* O = (float*)d_out;
  dim3 grid(kS / 128, kH);
  dim3 block(512);
  hipLaunchKernelGGL(lf_attn_mfma, grid, block, 0, stream, Q, K, V, M, O);
}